// Round 4
// baseline (278.055 us; speedup 1.0000x reference)
//
#include <hip/hip_runtime.h>
#include <math.h>

// Problem: B=2, S=4096, D=512, H=4 (h-broadcast: out[b,h]=out[b,0])
// Pipeline: cast -> proj(Q,V fused z=2) -> S-GEMM(+exp,+rowsum) -> PV(+1/rowsum, x4 h)
// All three matmuls use gemm8: BM=256,BN=128,BK=64, 8 waves, counted-vmcnt pipeline.
#define SEQ 4096
#define DIM 512
#define NBATCH 2

typedef __bf16 bf16;
typedef __bf16 bf16x8 __attribute__((ext_vector_type(8)));
typedef __bf16 bf16x4 __attribute__((ext_vector_type(4)));
typedef float  f32x4  __attribute__((ext_vector_type(4)));

#define GLOAD_LDS16(g, l)                                                              \
  __builtin_amdgcn_global_load_lds((__attribute__((address_space(1))) void*)(g),       \
                                   (__attribute__((address_space(3))) void*)(l), 16, 0, 0)

static const long NQ_ = (long)NBATCH * SEQ * DIM;  // 4,194,304
static const long NW_ = (long)DIM * DIM;           // 262,144
#define QSCALE 0.04419417382415922f                 // 1/sqrt(512)

// ---------------------------------------------------------------------------
// Fused f32 -> bf16 casts
// ---------------------------------------------------------------------------
__device__ __forceinline__ void cvt4(const float* __restrict__ s, bf16* __restrict__ d) {
  f32x4 x = *(const f32x4*)s;
  bf16x4 y;
  y[0] = (bf16)x[0]; y[1] = (bf16)x[1]; y[2] = (bf16)x[2]; y[3] = (bf16)x[3];
  *(bf16x4*)d = y;
}

__global__ __launch_bounds__(256)
void cast5(const float* __restrict__ q, const float* __restrict__ k,
           const float* __restrict__ v, const float* __restrict__ Wq,
           const float* __restrict__ Wv,
           bf16* __restrict__ qb, bf16* __restrict__ kb, bf16* __restrict__ vb,
           bf16* __restrict__ wqb, bf16* __restrict__ wvb) {
  long tid = blockIdx.x * 256L + threadIdx.x;
  long nth = gridDim.x * 256L;
  for (long i = tid * 4; i < NQ_; i += nth * 4) {
    cvt4(q + i, qb + i);
    cvt4(k + i, kb + i);
    cvt4(v + i, vb + i);
  }
  for (long i = tid * 4; i < NW_; i += nth * 4) {
    cvt4(Wq + i, wqb + i);
    cvt4(Wv + i, wvb + i);
  }
}

__global__ __launch_bounds__(256)
void zero_f32(float* __restrict__ p, int n) {
  int i = blockIdx.x * 256 + threadIdx.x;
  if (i < n) p[i] = 0.0f;
}

// ---------------------------------------------------------------------------
// gemm8<OUT>: C[M,N] = A[M,K] * Bt[N,K]^T with K-contiguous operands.
// BM=256, BN=128, BK=64. 512 threads = 8 waves as 4M x 2N (per-wave 64x64).
// Register-decoupled LDS double-buffer + counted vmcnt(6) (T3/T4), setprio
// (T5), chunk-XOR swizzle both-sides (T2, rule #21), XCD swizzle (T1).
// Per-thread staging: A 4 + B 2 = 6 global_load_lds per K-tile.
// OUT=0: projections, blockIdx.z in {0:Q, 1:V}. z=0: C=(acc+bq)*QSCALE
//        row-major; z=1: C=Vt transposed store (acc+bv).
// OUT=1: E = exp(acc) -> bf16 row-major + rowsum atomics (Q pre-scaled).
// OUT=2: f32 out = acc/rowsum[row], broadcast to 4 h planes.
// ---------------------------------------------------------------------------
template <int OUT>
__global__ __launch_bounds__(512, 2)
void gemm8(const bf16* __restrict__ A, const bf16* __restrict__ Bt,
           void* __restrict__ Cv, const float* __restrict__ bias0,
           const float* __restrict__ bias1, float* __restrict__ rowsum,
           int N, int K, long sB) {
  __shared__ __align__(16) bf16 lA[2][256 * 64];
  __shared__ __align__(16) bf16 lB[2][128 * 64];
  const int t = threadIdx.x;
  const int l = t & 63, w = t >> 6;

  // T1: bijective XCD swizzle over the (x=m-tiles, y=n-tiles) grid (nwg%8==0)
  const unsigned bid = blockIdx.y * gridDim.x + blockIdx.x;
  const unsigned nwg = gridDim.x * gridDim.y;
  const unsigned q8 = nwg >> 3;
  const unsigned swz = (bid & 7) * q8 + (bid >> 3);
  const long m0 = (long)(swz % gridDim.x) * 256;
  const long n0 = (long)(swz / gridDim.x) * 128;

  const int z = blockIdx.z;
  if constexpr (OUT == 0) {
    A += (long)z * NQ_;
    Bt += (long)z * NW_;
  } else {
    Bt += (m0 >> 12) * sB;  // batch-select (m-tiles never straddle batches)
  }

  const int wr = (w >> 1) * 64;  // wave row in [0,256)
  const int wc = (w & 1) * 64;   // wave col in [0,128)
  const int lr = l & 15, lg = l >> 4;

  // staging sources: slot s holds row=s>>3, global k-chunk (s&7)^(row&7)
  const bf16* gA[4];
  const bf16* gB[2];
#pragma unroll
  for (int i = 0; i < 4; ++i) {
    int s = i * 512 + t, row = s >> 3, kc = (s & 7) ^ (row & 7);
    gA[i] = A + (m0 + row) * (long)K + kc * 8;
  }
#pragma unroll
  for (int i = 0; i < 2; ++i) {
    int s = i * 512 + t, row = s >> 3, kc = (s & 7) ^ (row & 7);
    gB[i] = Bt + (n0 + row) * (long)K + kc * 8;
  }

  // ds_read offsets (elems): row*64 + ((ks*4+lg)^(row&7))*8, row&7 == lr&7
  int offA[4][2], offB[4][2];
#pragma unroll
  for (int m = 0; m < 4; ++m)
#pragma unroll
    for (int ks = 0; ks < 2; ++ks)
      offA[m][ks] = (wr + m * 16 + lr) * 64 + (((ks * 4 + lg) ^ (lr & 7)) * 8);
#pragma unroll
  for (int n = 0; n < 4; ++n)
#pragma unroll
    for (int ks = 0; ks < 2; ++ks)
      offB[n][ks] = (wc + n * 16 + lr) * 64 + (((ks * 4 + lg) ^ (lr & 7)) * 8);

  // stage one K-tile (6 loads/thread)
  auto stage6 = [&](long koff, bf16* dA, bf16* dB) {
#pragma unroll
    for (int i = 0; i < 4; ++i) GLOAD_LDS16(gA[i] + koff, dA + (i * 512 + w * 64) * 8);
#pragma unroll
    for (int i = 0; i < 2; ++i) GLOAD_LDS16(gB[i] + koff, dB + (i * 512 + w * 64) * 8);
  };

  f32x4 acc[4][4] = {};
  const int NT = K >> 6;

  // prologue: tiles 0 and 1 in flight; wait tile 0 only (vmcnt(6))
  stage6(0, lA[0], lB[0]);
  stage6(64, lA[1], lB[1]);
  asm volatile("s_waitcnt vmcnt(6)" ::: "memory");
  __builtin_amdgcn_sched_barrier(0);
  __builtin_amdgcn_s_barrier();
  __builtin_amdgcn_sched_barrier(0);

  for (int tt = 0; tt < NT; ++tt) {
    const int cur = tt & 1;
    const bf16* bufA = lA[cur];
    const bf16* bufB = lB[cur];
    // ---- ks0 fragment reads + MFMA
    bf16x8 a0[4], b0[4];
#pragma unroll
    for (int m = 0; m < 4; ++m) a0[m] = *(const bf16x8*)(bufA + offA[m][0]);
#pragma unroll
    for (int n = 0; n < 4; ++n) b0[n] = *(const bf16x8*)(bufB + offB[n][0]);
    asm volatile("s_waitcnt lgkmcnt(0)" ::: "memory");
    __builtin_amdgcn_sched_barrier(0);
    __builtin_amdgcn_s_setprio(1);
#pragma unroll
    for (int m = 0; m < 4; ++m)
#pragma unroll
      for (int n = 0; n < 4; ++n)
        acc[m][n] = __builtin_amdgcn_mfma_f32_16x16x32_bf16(a0[m], b0[n], acc[m][n], 0, 0, 0);
    __builtin_amdgcn_s_setprio(0);
    // ---- ks1 fragment reads; then buf is fully consumed -> barrier
    bf16x8 a1[4], b1[4];
#pragma unroll
    for (int m = 0; m < 4; ++m) a1[m] = *(const bf16x8*)(bufA + offA[m][1]);
#pragma unroll
    for (int n = 0; n < 4; ++n) b1[n] = *(const bf16x8*)(bufB + offB[n][1]);
    asm volatile("s_waitcnt lgkmcnt(0)" ::: "memory");
    __builtin_amdgcn_sched_barrier(0);
    __builtin_amdgcn_s_barrier();
    __builtin_amdgcn_sched_barrier(0);
    // ---- prefetch tile t+2 into the just-freed buffer, MFMA ks1 underneath
    if (tt + 2 < NT) stage6((long)(tt + 2) * 64, lA[cur], lB[cur]);
    __builtin_amdgcn_s_setprio(1);
#pragma unroll
    for (int m = 0; m < 4; ++m)
#pragma unroll
      for (int n = 0; n < 4; ++n)
        acc[m][n] = __builtin_amdgcn_mfma_f32_16x16x32_bf16(a1[m], b1[n], acc[m][n], 0, 0, 0);
    __builtin_amdgcn_s_setprio(0);
    // ---- counted drain: tile t+1's loads complete, t+2's stay in flight
    if (tt + 2 < NT) {
      asm volatile("s_waitcnt vmcnt(6)" ::: "memory");
    } else if (tt + 1 < NT) {
      asm volatile("s_waitcnt vmcnt(0)" ::: "memory");
    }
    if (tt + 1 < NT) {
      __builtin_amdgcn_sched_barrier(0);
      __builtin_amdgcn_s_barrier();
      __builtin_amdgcn_sched_barrier(0);
    }
  }

  // ------------------------------ epilogues ------------------------------
  if constexpr (OUT == 0) {
    if (z == 0) {
      bf16* C = (bf16*)Cv;  // Qbf [8192,512] row-major
#pragma unroll
      for (int n = 0; n < 4; ++n) {
        const long col = n0 + wc + n * 16 + lr;
        const float bcol = bias0[col];
#pragma unroll
        for (int m = 0; m < 4; ++m) {
          const long rowb = m0 + wr + m * 16 + lg * 4;
#pragma unroll
          for (int r = 0; r < 4; ++r)
            C[(rowb + r) * (long)DIM + col] = (bf16)((acc[m][n][r] + bcol) * QSCALE);
        }
      }
    } else {
      bf16* Vt = (bf16*)Cv + NQ_;  // [B, D, S] transposed
#pragma unroll
      for (int n = 0; n < 4; ++n) {
        const long col = n0 + wc + n * 16 + lr;
        const float bcol = bias1[col];
#pragma unroll
        for (int m = 0; m < 4; ++m) {
          const long rowb = m0 + wr + m * 16 + lg * 4;
#pragma unroll
          for (int r = 0; r < 4; ++r) {
            long gr = rowb + r, bb = gr >> 12, ss = gr & 4095;
            Vt[bb * (long)(DIM * SEQ) + col * (long)SEQ + ss] = (bf16)(acc[m][n][r] + bcol);
          }
        }
      }
    }
  } else if constexpr (OUT == 1) {
    bf16* C = (bf16*)Cv;
#pragma unroll
    for (int m = 0; m < 4; ++m) {
      const long rowb = m0 + wr + m * 16 + lg * 4;
#pragma unroll
      for (int r = 0; r < 4; ++r) {
        float rsum = 0.0f;
#pragma unroll
        for (int n = 0; n < 4; ++n) {
          const long col = n0 + wc + n * 16 + lr;
          float e = __expf(acc[m][n][r]);
          bf16 eb = (bf16)e;
          C[(rowb + r) * (long)N + col] = eb;
          rsum += (float)eb;
        }
        rsum += __shfl_xor(rsum, 1);
        rsum += __shfl_xor(rsum, 2);
        rsum += __shfl_xor(rsum, 4);
        rsum += __shfl_xor(rsum, 8);
        if (lr == 0) atomicAdd(rowsum + rowb + r, rsum);
      }
    }
  } else {
    float* o = (float*)Cv;  // out base (batched: both batches via gr>>12)
#pragma unroll
    for (int m = 0; m < 4; ++m) {
      const long rowb = m0 + wr + m * 16 + lg * 4;
#pragma unroll
      for (int r = 0; r < 4; ++r) {
        const long gr = rowb + r, bb = gr >> 12, ss = gr & 4095;
        const float inv = 1.0f / rowsum[gr];
        float* p0 = o + bb * (4L * SEQ * DIM) + ss * (long)DIM;
#pragma unroll
        for (int n = 0; n < 4; ++n) {
          const long col = n0 + wc + n * 16 + lr;
          float vv = acc[m][n][r] * inv;
          p0[col] = vv;
          p0[col + 1L * SEQ * DIM] = vv;
          p0[col + 2L * SEQ * DIM] = vv;
          p0[col + 3L * SEQ * DIM] = vv;
        }
      }
    }
  }
}

// ---------------------------------------------------------------------------
// Host launch
// ---------------------------------------------------------------------------
extern "C" void kernel_launch(void* const* d_in, const int* in_sizes, int n_in,
                              void* d_out, int out_size, void* d_ws, size_t ws_size,
                              hipStream_t stream) {
  const float* q  = (const float*)d_in[0];
  const float* k  = (const float*)d_in[1];
  const float* v  = (const float*)d_in[2];
  const float* Wq = (const float*)d_in[3];
  const float* bq = (const float*)d_in[4];
  const float* Wv = (const float*)d_in[5];
  const float* bv = (const float*)d_in[6];
  float* outp = (float*)d_out;

  // ws layout (Qbf and Vt adjacent so proj can address C + z*NQ_)
  bf16* Qbf = (bf16*)d_ws;       // [8192, 512] scaled Q projection
  bf16* Vt  = Qbf + NQ_;         // [B, D, S] V projection transposed
  bf16* Kbf = Vt + NQ_;          // [8192, 512] k cast
  bf16* Wqb = Kbf + NQ_;
  bf16* Wvb = Wqb + NW_;
  bf16* Sbuf = Wvb + NW_;        // E = exp(scores), bf16
  const size_t baseBytes = (size_t)((char*)Sbuf - (char*)d_ws);     // 26,214,400
  const bool batched = ws_size >= baseBytes + 2ULL * SEQ * SEQ * 2; // +64 MiB
  bf16* qb = Sbuf;               // cast temporaries (contiguous: vb = qb + NQ_)
  bf16* vb = Sbuf + NQ_;
  float* rowsum = (float*)Wqb;   // dead after projections; 8192 f32 = 32 KB

  const long sQK = (long)SEQ * DIM;      // 2,097,152
  const long sO  = 4L * SEQ * DIM;       // 8,388,608 (H*S*D)

  cast5<<<dim3(2048), dim3(256), 0, stream>>>(q, k, v, Wq, Wv, qb, Kbf, vb, Wqb, Wvb);
  // fused Q/V projections: z=0 -> Qbf (scaled), z=1 -> Vt (transposed)
  gemm8<0><<<dim3(32, 4, 2), dim3(512), 0, stream>>>(
      qb, Wqb, Qbf, bq, bv, nullptr, 512, 512, 0);
  if (batched) {
    zero_f32<<<dim3(32), dim3(256), 0, stream>>>(rowsum, NBATCH * SEQ);
    gemm8<1><<<dim3(32, 32, 1), dim3(512), 0, stream>>>(
        Qbf, Kbf, Sbuf, nullptr, nullptr, rowsum, 4096, 512, sQK);
    gemm8<2><<<dim3(32, 4, 1), dim3(512), 0, stream>>>(
        Sbuf, Vt, outp, nullptr, nullptr, rowsum, 512, 4096, sQK);
  } else {
    for (int b = 0; b < 2; ++b) {
      zero_f32<<<dim3(16), dim3(256), 0, stream>>>(rowsum, SEQ);
      gemm8<1><<<dim3(16, 32, 1), dim3(512), 0, stream>>>(
          Qbf + b * sQK, Kbf + b * sQK, Sbuf, nullptr, nullptr, rowsum, 4096, 512, sQK);
      gemm8<2><<<dim3(16, 4, 1), dim3(512), 0, stream>>>(
          Sbuf, Vt + b * sQK, outp + b * sO, nullptr, nullptr, rowsum, 512, 4096, sQK);
    }
  }
}

// Round 5
// 231.086 us; speedup vs baseline: 1.2033x; 1.2033x over previous
//
#include <hip/hip_runtime.h>
#include <math.h>

// Problem: B=2, S=4096, D=512, H=4 (h-broadcast: out[b,h]=out[b,0])
// Pipeline: cast -> proj(Q,V fused z=2) -> S-GEMM(+exp,+rowsum) -> PV(+1/rowsum, x4 h)
// gemm3: 3-stage rotating LDS pipeline, BK=32, one s_barrier + one counted
// vmcnt per K-tile, m201 ordering (ds_reads -> stage -> MFMA -> fences).
#define SEQ 4096
#define DIM 512
#define NBATCH 2

typedef __bf16 bf16;
typedef __bf16 bf16x8 __attribute__((ext_vector_type(8)));
typedef __bf16 bf16x4 __attribute__((ext_vector_type(4)));
typedef float  f32x4  __attribute__((ext_vector_type(4)));

#define GLOAD_LDS16(g, l)                                                              \
  __builtin_amdgcn_global_load_lds((__attribute__((address_space(1))) void*)(g),       \
                                   (__attribute__((address_space(3))) void*)(l), 16, 0, 0)

#define VMCNT(n) asm volatile("s_waitcnt vmcnt(" #n ")" ::: "memory")

static const long NQ_ = (long)NBATCH * SEQ * DIM;  // 4,194,304
static const long NW_ = (long)DIM * DIM;           // 262,144
#define QSCALE 0.04419417382415922f                 // 1/sqrt(512)

// ---------------------------------------------------------------------------
// Fused f32 -> bf16 casts
// ---------------------------------------------------------------------------
__device__ __forceinline__ void cvt4(const float* __restrict__ s, bf16* __restrict__ d) {
  f32x4 x = *(const f32x4*)s;
  bf16x4 y;
  y[0] = (bf16)x[0]; y[1] = (bf16)x[1]; y[2] = (bf16)x[2]; y[3] = (bf16)x[3];
  *(bf16x4*)d = y;
}

__global__ __launch_bounds__(256)
void cast5(const float* __restrict__ q, const float* __restrict__ k,
           const float* __restrict__ v, const float* __restrict__ Wq,
           const float* __restrict__ Wv,
           bf16* __restrict__ qb, bf16* __restrict__ kb, bf16* __restrict__ vb,
           bf16* __restrict__ wqb, bf16* __restrict__ wvb) {
  long tid = blockIdx.x * 256L + threadIdx.x;
  long nth = gridDim.x * 256L;
  for (long i = tid * 4; i < NQ_; i += nth * 4) {
    cvt4(q + i, qb + i);
    cvt4(k + i, kb + i);
    cvt4(v + i, vb + i);
  }
  for (long i = tid * 4; i < NW_; i += nth * 4) {
    cvt4(Wq + i, wqb + i);
    cvt4(Wv + i, wvb + i);
  }
}

__global__ __launch_bounds__(256)
void zero_f32(float* __restrict__ p, int n) {
  int i = blockIdx.x * 256 + threadIdx.x;
  if (i < n) p[i] = 0.0f;
}

// ---------------------------------------------------------------------------
// gemm3<BM,BN,OUT>: C[M,N] = A[M,K]*Bt[N,K]^T, K-contiguous operands, BK=32.
// 512 threads = 8 waves as 2M x 4N; per-wave (BM/2) x (BN/4).
// 3 rotating LDS buffers; per K-tile: {ds_read frags; stage tile t+2;
// setprio+MFMA; vmcnt(NLD); s_barrier}. vmcnt never drains to 0 in-loop.
// Swizzle (BK=32, 4 chunks/row): chunk ^= (row>>1)&3, applied both on the
// global staging source and the ds_read address (rule #21) -> 2-way max.
// OUT=0: projections, z=0: Q=(acc+bq)*QSCALE row-major; z=1: Vt=(acc+bv) T.
// OUT=1: E=exp(acc) bf16 row-major + rowsum atomics.  OUT=2: f32 out =
// acc/rowsum[row] broadcast to 4 h planes.
// ---------------------------------------------------------------------------
template <int BM, int BN, int OUT>
__global__ __launch_bounds__(512, (BM == 256 ? 2 : 4))
void gemm3(const bf16* __restrict__ A, const bf16* __restrict__ Bt,
           void* __restrict__ Cv, const float* __restrict__ bias0,
           const float* __restrict__ bias1, float* __restrict__ rowsum,
           int N, int K, long sB) {
  constexpr int MF = BM / 32;   // m-frags per wave
  constexpr int NF = BN / 64;   // n-frags per wave
  constexpr int LA = BM / 128;  // A gloads / thread / tile
  constexpr int LB = BN / 128;  // B gloads / thread / tile
  constexpr int NLD = LA + LB;
  constexpr int ASZ = BM * 32;  // elems per A region
  constexpr int BSZ = BN * 32;
  __shared__ __align__(16) bf16 lds[3][ASZ + BSZ];

  const int t = threadIdx.x;
  const int l = t & 63, w = t >> 6;
  const int lr = l & 15, lg = l >> 4;

  // T1: bijective XCD swizzle (all grids have nwg % 8 == 0)
  const unsigned bid = blockIdx.y * gridDim.x + blockIdx.x;
  const unsigned nwg = gridDim.x * gridDim.y;
  const unsigned q8 = nwg >> 3;
  const unsigned swz = (bid & 7) * q8 + (bid >> 3);
  const long m0 = (long)(swz % gridDim.x) * BM;
  const long n0 = (long)(swz / gridDim.x) * BN;

  const int z = blockIdx.z;
  if constexpr (OUT == 0) {
    A += (long)z * NQ_;
    Bt += (long)z * NW_;
  } else {
    Bt += (m0 >> 12) * sB;  // batch-select (m-tiles never straddle batches)
  }

  const int wr = (w >> 2) * (BM / 2);  // wave row base
  const int wc = (w & 3) * (BN / 4);   // wave col base

  // global staging sources: slot s -> row=s>>2, src chunk (s&3)^((row>>1)&3)
  const bf16* gA[LA];
  const bf16* gB[LB];
#pragma unroll
  for (int i = 0; i < LA; ++i) {
    int s = i * 512 + t, row = s >> 2, c = (s & 3) ^ ((row >> 1) & 3);
    gA[i] = A + (m0 + row) * (long)K + c * 8;
  }
#pragma unroll
  for (int i = 0; i < LB; ++i) {
    int s = i * 512 + t, row = s >> 2, c = (s & 3) ^ ((row >> 1) & 3);
    gB[i] = Bt + (n0 + row) * (long)K + c * 8;
  }

  // ds_read elem offsets: row*32 + (lg ^ ((lr>>1)&3))*8  (row bits1-2 == lr's)
  int offA[MF], offB[NF];
#pragma unroll
  for (int mf = 0; mf < MF; ++mf)
    offA[mf] = (wr + mf * 16 + lr) * 32 + ((lg ^ ((lr >> 1) & 3)) * 8);
#pragma unroll
  for (int nf = 0; nf < NF; ++nf)
    offB[nf] = ASZ + (wc + nf * 16 + lr) * 32 + ((lg ^ ((lr >> 1) & 3)) * 8);

  auto stage = [&](int tt, int bidx) {
    const long ko = (long)tt * 32;
#pragma unroll
    for (int i = 0; i < LA; ++i)
      GLOAD_LDS16(gA[i] + ko, &lds[bidx][(i * 512 + w * 64) * 8]);
#pragma unroll
    for (int i = 0; i < LB; ++i)
      GLOAD_LDS16(gB[i] + ko, &lds[bidx][ASZ + (i * 512 + w * 64) * 8]);
  };

  f32x4 acc[MF][NF] = {};
  const int NT = K >> 5;  // K-tiles of 32

  // prologue: tiles 0,1 in flight; wait tile 0; sync
  stage(0, 0);
  stage(1, 1);
  if constexpr (NLD == 4) VMCNT(4); else VMCNT(2);
  __builtin_amdgcn_sched_barrier(0);
  __builtin_amdgcn_s_barrier();
  __builtin_amdgcn_sched_barrier(0);

  int cur = 0, stg = 2;
  for (int tt = 0; tt < NT - 2; ++tt) {
    // ds_read current tile's fragments (reads BEFORE stage: WAR only)
    bf16x8 af[MF], bfn[NF];
#pragma unroll
    for (int mf = 0; mf < MF; ++mf) af[mf] = *(const bf16x8*)(&lds[cur][offA[mf]]);
#pragma unroll
    for (int nf = 0; nf < NF; ++nf) bfn[nf] = *(const bf16x8*)(&lds[cur][offB[nf]]);
    // issue prefetch of tile tt+2 into the buffer dead since tile tt-1
    stage(tt + 2, stg);
    // MFMA (compiler inserts fine-grained lgkmcnt for the ds_read deps)
    __builtin_amdgcn_s_setprio(1);
#pragma unroll
    for (int mf = 0; mf < MF; ++mf)
#pragma unroll
      for (int nf = 0; nf < NF; ++nf)
        acc[mf][nf] = __builtin_amdgcn_mfma_f32_16x16x32_bf16(af[mf], bfn[nf], acc[mf][nf], 0, 0, 0);
    __builtin_amdgcn_s_setprio(0);
    // counted drain: tile tt+1 landed, tile tt+2 stays in flight
    if constexpr (NLD == 4) VMCNT(4); else VMCNT(2);
    __builtin_amdgcn_sched_barrier(0);
    __builtin_amdgcn_s_barrier();
    __builtin_amdgcn_sched_barrier(0);
    cur = (cur == 2) ? 0 : cur + 1;
    stg = (stg == 2) ? 0 : stg + 1;
  }
  // tile NT-2: no prefetch; full drain so tile NT-1 is ready
  {
    bf16x8 af[MF], bfn[NF];
#pragma unroll
    for (int mf = 0; mf < MF; ++mf) af[mf] = *(const bf16x8*)(&lds[cur][offA[mf]]);
#pragma unroll
    for (int nf = 0; nf < NF; ++nf) bfn[nf] = *(const bf16x8*)(&lds[cur][offB[nf]]);
    __builtin_amdgcn_s_setprio(1);
#pragma unroll
    for (int mf = 0; mf < MF; ++mf)
#pragma unroll
      for (int nf = 0; nf < NF; ++nf)
        acc[mf][nf] = __builtin_amdgcn_mfma_f32_16x16x32_bf16(af[mf], bfn[nf], acc[mf][nf], 0, 0, 0);
    __builtin_amdgcn_s_setprio(0);
    VMCNT(0);
    __builtin_amdgcn_sched_barrier(0);
    __builtin_amdgcn_s_barrier();
    __builtin_amdgcn_sched_barrier(0);
    cur = (cur == 2) ? 0 : cur + 1;
  }
  // tile NT-1
  {
    bf16x8 af[MF], bfn[NF];
#pragma unroll
    for (int mf = 0; mf < MF; ++mf) af[mf] = *(const bf16x8*)(&lds[cur][offA[mf]]);
#pragma unroll
    for (int nf = 0; nf < NF; ++nf) bfn[nf] = *(const bf16x8*)(&lds[cur][offB[nf]]);
#pragma unroll
    for (int mf = 0; mf < MF; ++mf)
#pragma unroll
      for (int nf = 0; nf < NF; ++nf)
        acc[mf][nf] = __builtin_amdgcn_mfma_f32_16x16x32_bf16(af[mf], bfn[nf], acc[mf][nf], 0, 0, 0);
  }

  // ------------------------------ epilogues ------------------------------
  if constexpr (OUT == 0) {
    if (z == 0) {
      bf16* C = (bf16*)Cv;  // Qbf [8192,512] row-major
#pragma unroll
      for (int nf = 0; nf < NF; ++nf) {
        const long col = n0 + wc + nf * 16 + lr;
        const float bcol = bias0[col];
#pragma unroll
        for (int mf = 0; mf < MF; ++mf) {
          const long rowb = m0 + wr + mf * 16 + lg * 4;
#pragma unroll
          for (int r = 0; r < 4; ++r)
            C[(rowb + r) * (long)DIM + col] = (bf16)((acc[mf][nf][r] + bcol) * QSCALE);
        }
      }
    } else {
      bf16* Vt = (bf16*)Cv + NQ_;  // [B, D, S] transposed
#pragma unroll
      for (int nf = 0; nf < NF; ++nf) {
        const long col = n0 + wc + nf * 16 + lr;
        const float bcol = bias1[col];
#pragma unroll
        for (int mf = 0; mf < MF; ++mf) {
          const long rowb = m0 + wr + mf * 16 + lg * 4;
#pragma unroll
          for (int r = 0; r < 4; ++r) {
            long gr = rowb + r, bb = gr >> 12, ss = gr & 4095;
            Vt[bb * (long)(DIM * SEQ) + col * (long)SEQ + ss] = (bf16)(acc[mf][nf][r] + bcol);
          }
        }
      }
    }
  } else if constexpr (OUT == 1) {
    bf16* C = (bf16*)Cv;
#pragma unroll
    for (int mf = 0; mf < MF; ++mf) {
      const long rowb = m0 + wr + mf * 16 + lg * 4;
#pragma unroll
      for (int r = 0; r < 4; ++r) {
        float rsum = 0.0f;
#pragma unroll
        for (int nf = 0; nf < NF; ++nf) {
          const long col = n0 + wc + nf * 16 + lr;
          float e = __expf(acc[mf][nf][r]);
          bf16 eb = (bf16)e;
          C[(rowb + r) * (long)N + col] = eb;
          rsum += (float)eb;
        }
        rsum += __shfl_xor(rsum, 1);
        rsum += __shfl_xor(rsum, 2);
        rsum += __shfl_xor(rsum, 4);
        rsum += __shfl_xor(rsum, 8);
        if (lr == 0) atomicAdd(rowsum + rowb + r, rsum);
      }
    }
  } else {
    float* o = (float*)Cv;
#pragma unroll
    for (int mf = 0; mf < MF; ++mf) {
      const long rowb = m0 + wr + mf * 16 + lg * 4;
#pragma unroll
      for (int r = 0; r < 4; ++r) {
        const long gr = rowb + r, bb = gr >> 12, ss = gr & 4095;
        const float inv = 1.0f / rowsum[gr];
        float* p0 = o + bb * (4L * SEQ * DIM) + ss * (long)DIM;
#pragma unroll
        for (int nf = 0; nf < NF; ++nf) {
          const long col = n0 + wc + nf * 16 + lr;
          float vv = acc[mf][nf][r] * inv;
          p0[col] = vv;
          p0[col + 1L * SEQ * DIM] = vv;
          p0[col + 2L * SEQ * DIM] = vv;
          p0[col + 3L * SEQ * DIM] = vv;
        }
      }
    }
  }
}

// ---------------------------------------------------------------------------
// Host launch
// ---------------------------------------------------------------------------
extern "C" void kernel_launch(void* const* d_in, const int* in_sizes, int n_in,
                              void* d_out, int out_size, void* d_ws, size_t ws_size,
                              hipStream_t stream) {
  const float* q  = (const float*)d_in[0];
  const float* k  = (const float*)d_in[1];
  const float* v  = (const float*)d_in[2];
  const float* Wq = (const float*)d_in[3];
  const float* bq = (const float*)d_in[4];
  const float* Wv = (const float*)d_in[5];
  const float* bv = (const float*)d_in[6];
  float* outp = (float*)d_out;

  bf16* Qbf = (bf16*)d_ws;       // [8192, 512] scaled Q projection
  bf16* Vt  = Qbf + NQ_;         // [B, D, S] V projection transposed
  bf16* Kbf = Vt + NQ_;          // [8192, 512] k cast
  bf16* Wqb = Kbf + NQ_;
  bf16* Wvb = Wqb + NW_;
  bf16* Sbuf = Wvb + NW_;        // E = exp(scores), bf16
  const size_t baseBytes = (size_t)((char*)Sbuf - (char*)d_ws);     // 26,214,400
  const bool batched = ws_size >= baseBytes + 2ULL * SEQ * SEQ * 2; // +64 MiB
  bf16* qb = Sbuf;               // cast temporaries (vb = qb + NQ_)
  bf16* vb = Sbuf + NQ_;
  float* rowsum = (float*)Wqb;   // dead after projections; 8192 f32

  const long sQK = (long)SEQ * DIM;      // 2,097,152
  const long sO  = 4L * SEQ * DIM;       // 8,388,608 (H*S*D)

  cast5<<<dim3(2048), dim3(256), 0, stream>>>(q, k, v, Wq, Wv, qb, Kbf, vb, Wqb, Wvb);
  // fused Q/V projections: z=0 -> Qbf (scaled), z=1 -> Vt (transposed)
  gemm3<128, 128, 0><<<dim3(64, 4, 2), dim3(512), 0, stream>>>(
      qb, Wqb, Qbf, bq, bv, nullptr, 512, 512, 0);
  if (batched) {
    zero_f32<<<dim3(32), dim3(256), 0, stream>>>(rowsum, NBATCH * SEQ);
    gemm3<256, 256, 1><<<dim3(32, 16, 1), dim3(512), 0, stream>>>(
        Qbf, Kbf, Sbuf, nullptr, nullptr, rowsum, 4096, 512, sQK);
    gemm3<128, 128, 2><<<dim3(64, 4, 1), dim3(512), 0, stream>>>(
        Sbuf, Vt, outp, nullptr, nullptr, rowsum, 512, 4096, sQK);
  } else {
    for (int b = 0; b < 2; ++b) {
      zero_f32<<<dim3(16), dim3(256), 0, stream>>>(rowsum, SEQ);
      gemm3<256, 256, 1><<<dim3(16, 16, 1), dim3(512), 0, stream>>>(
          Qbf + b * sQK, Kbf + b * sQK, Sbuf, nullptr, nullptr, rowsum, 4096, 512, sQK);
      gemm3<128, 128, 2><<<dim3(32, 4, 1), dim3(512), 0, stream>>>(
          Sbuf, Vt + b * sQK, outp + b * sO, nullptr, nullptr, rowsum, 512, 4096, sQK);
    }
  }
}